// Round 10
// baseline (165.489 us; speedup 1.0000x reference)
//
#include <hip/hip_runtime.h>

// Conv2d 3x3 pad1 stride1, x[1,256,224,224] f32, w[256,256,3,3] f32 -> out[256,224,224] f32
// Implicit GEMM: M=256 (co), N=50176 (h*224+w), K=2304 (tap-major: k = (dh*3+dw)*256 + ci)
// R16: issue-early staging on the R13 champion (71.1us, conflicts=0). R12==R13 proved
//      sync style irrelevant; binding stall = per-half vmcnt join with only ~1 half-phase
//      (~1240cyc) of load slack vs ~900cyc HBM latency. Change ONLY the stage schedule:
//      all 8 of kt+1's loads issue at the TOP of iter kt (buffer 1-P, sealed by kt-1's
//      trailing barrier) -> in-flight 2-3 halves. vmcnt ladder: kappa0-end vmcnt(8)
//      (retires kt's k1; outstanding <= kt.k1 4 + kt+1 8), kt-end vmcnt(4) (retires
//      kt+1's k0). Never 0 in loop. Split frag arrays afA/afB kill the WAR serialization
//      of mi4-7 reads against half-0 MFMAs. LDS layout/swizzle/acc order byte-identical
//      to R13 -> bitwise-same output, conflicts must stay 0.

#define H 224
#define W 224
#define NPOS (H*W)          // 50176
#define CI 256
#define CO 256
#define KDIM 2304
#define HP 226              // padded
#define XP_ELEMS (HP*HP*CI) // 13,075,456 shorts
#define AP_ELEMS (CO*KDIM)  // 589,824 shorts

typedef __bf16 bf16x8 __attribute__((ext_vector_type(8)));
typedef float f32x4 __attribute__((ext_vector_type(4)));
typedef unsigned short u16x4 __attribute__((ext_vector_type(4)));
typedef unsigned short u16x8 __attribute__((ext_vector_type(8)));

__device__ __forceinline__ unsigned short f2bf(float f) {
    unsigned int u = __float_as_uint(f);
    u += 0x7fff + ((u >> 16) & 1);   // round-to-nearest-even
    return (unsigned short)(u >> 16);
}

__device__ __forceinline__ void load_lds16(const unsigned short* g, unsigned short* l) {
    __builtin_amdgcn_global_load_lds(
        (const __attribute__((address_space(1))) void*)g,
        (__attribute__((address_space(3))) void*)l,
        16, 0, 0);
}

// ---- fused prep (unchanged from R8): xtrans + weight transform + border zero ----
#define XT_BLOCKS 3136      // 784 * 4
#define WT_BLOCKS 256
#define BORDER_V8 28800     // 230,400 shorts / 8
#define ROW_V8 7232         // 226*256/8
__global__ void prep_kernel(const float* __restrict__ x, const float* __restrict__ w,
                            unsigned short* __restrict__ ap, unsigned short* __restrict__ xp) {
    __shared__ unsigned short smem[64 * 68];
    const int bx = blockIdx.x;
    const int t = threadIdx.x;

    if (bx < XT_BLOCKS) {
        const unsigned int pBase = (unsigned int)(bx % 784) * 64;
        const unsigned int ciBase = (unsigned int)(bx / 784) * 64;
        {
            const int p4 = (t & 15) * 4;
            const int c0 = t >> 4;               // 0..15
#pragma unroll
            for (int i = 0; i < 4; ++i) {
                const int ci_l = c0 + i * 16;
                const f32x4 v = *(const f32x4*)&x[(ciBase + ci_l) * NPOS + pBase + p4];
                u16x4 s;
                s[0] = f2bf(v[0]); s[1] = f2bf(v[1]); s[2] = f2bf(v[2]); s[3] = f2bf(v[3]);
                *(u16x4*)&smem[ci_l * 68 + p4] = s;
            }
        }
        __syncthreads();
        {
            const int ci0 = (t & 7) * 8;
            const int pr = t >> 3;               // 0..31
#pragma unroll
            for (int j = 0; j < 2; ++j) {
                const int p_l = pr + j * 32;
                const unsigned int p = pBase + p_l;
                const unsigned int hi = p / W, wi = p - hi * W;
                u16x8 v;
#pragma unroll
                for (int k = 0; k < 8; ++k) v[k] = smem[(ci0 + k) * 68 + p_l];
                *(u16x8*)&xp[((hi + 1) * HP + (wi + 1)) * CI + ciBase + ci0] = v;
            }
        }
    } else if (bx < XT_BLOCKS + WT_BLOCKS) {
        const int co = bx - XT_BLOCKS;
        const float* wc = w + co * KDIM;
#pragma unroll
        for (int i = 0; i < 9; ++i)
            smem[i * 256 + t] = f2bf(wc[i * 256 + t]);
        __syncthreads();
        unsigned short* apc = ap + co * KDIM;
#pragma unroll
        for (int tap = 0; tap < 9; ++tap)
            apc[tap * 256 + t] = smem[t * 9 + tap];
    } else {
        const int idx = (bx - XT_BLOCKS - WT_BLOCKS) * 256 + t;
        if (idx < BORDER_V8) {
            unsigned short* p;
            if (idx < 2 * ROW_V8) {
                const int r = idx / ROW_V8;
                const int off = idx - r * ROW_V8;
                p = xp + r * (225 * HP * CI) + off * 8;
            } else {
                const int i2 = idx - 2 * ROW_V8;
                const int seg = i2 >> 5;
                const int o = i2 & 31;
                const int hp = 1 + (seg >> 1);
                const int wp = (seg & 1) * 225;
                p = xp + (hp * HP + wp) * CI + o * 8;
            }
            *(u16x8*)p = (u16x8){0, 0, 0, 0, 0, 0, 0, 0};
        }
    }
}

// ---- implicit GEMM, 256x256 tile, BK=64, 8 waves (2Mx4N), wave-tile 128x64 ----
// MFMA 16x16x32 (R13 champion shape). LDS layout/swizzle identical to R12/R13:
//   A[pi][kappa] = 4 regions x 8192 shorts at [0,32768); B likewise at +32768.
//   Slot s of row r holds global chunk s ^ ((r&15)>>1 & 3); source pre-swizzle
//   c4 = (l&3)^((l>>3)&3); read slot quad^((ln15>>1)&3). Measured conflict-free (R12/R13).
// Staging (R16): all 8 loads of kt+1 (A0,B0,A1,B1 x 2) issue at iter-kt TOP into
//   buffer 1-P (readers sealed by kt-1's trailing barrier). Waits:
//   kappa0-end: vmcnt(8) [outstanding <= kt.k1(4)+kt+1(8)=12; retires kt's k1]
//   kt-end:     vmcnt(4) [outstanding = kt+1's 8; retires kt+1's k0]
//   tail kt=35: kappa0-end vmcnt(0), no trailing wait.
// Per kappa half: 12 ds_read_b128 (afA 4, afB 4, bfr 4 - distinct arrays) then 32 MFMA.

#define RDALL(base)                                                             \
    _Pragma("unroll")                                                           \
    for (int mi = 0; mi < 4; ++mi)                                              \
        afA[mi] = *(const bf16x8*)&lds[(base) + arow + mi * 512];               \
    _Pragma("unroll")                                                           \
    for (int mi = 0; mi < 4; ++mi)                                              \
        afB[mi] = *(const bf16x8*)&lds[(base) + arow + (4 + mi) * 512];         \
    _Pragma("unroll")                                                           \
    for (int ni = 0; ni < 4; ++ni)                                              \
        bfr[ni] = *(const bf16x8*)&lds[(base) + brow + ni * 512];

#define MMH(half, afX)                                                          \
    __builtin_amdgcn_s_setprio(1);                                              \
    _Pragma("unroll")                                                           \
    for (int mi = 0; mi < 4; ++mi)                                              \
        _Pragma("unroll")                                                       \
        for (int ni = 0; ni < 4; ++ni)                                          \
            acc[(half) * 4 + mi][ni] = __builtin_amdgcn_mfma_f32_16x16x32_bf16( \
                afX[mi], bfr[ni], acc[(half) * 4 + mi][ni], 0, 0, 0);           \
    __builtin_amdgcn_s_setprio(0);

__global__ __launch_bounds__(512, 1) void gemm_conv_kernel(
    const unsigned short* __restrict__ Ap,   // [256][2304] bf16
    const unsigned short* __restrict__ Xp,   // [226][226][256] bf16
    float* __restrict__ out)                 // [256][50176]
{
    __shared__ unsigned short lds[65536];    // 128 KB

    const int tid = threadIdx.x;
    const int Nb = blockIdx.x;               // 0..195
    const int wave = tid >> 6;               // 0..7
    const int wm = wave >> 2;                // 0..1 (M half: 128 rows)
    const int wn = wave & 3;                 // 0..3 (N quarter: 64 cols)
    const int lane = tid & 63;
    const int ln15 = lane & 15;
    const int quad = lane >> 4;
    const int slot8 = (quad ^ ((ln15 >> 1) & 3)) * 8;    // proven conflict-free (R12)
    const int arow = (wm * 128 + ln15) * 32 + slot8;     // + (half*4+mi)*512
    const int brow = 32768 + (wn * 64 + ln15) * 32 + slot8;  // + ni*512

    // ---- staging sources (inverse swizzle pre-applied; unchanged from R12/R13) ----
    const int c4 = (tid & 3) ^ ((tid >> 3) & 3);
    const unsigned short* a_src[2];
    const unsigned short* b_src[2];
#pragma unroll
    for (int j = 0; j < 2; ++j) {
        const int r = j * 128 + (tid >> 2);              // 0..255
        a_src[j] = Ap + r * KDIM + c4 * 8;               // + kt*64 + kappa*32
        unsigned int p = Nb * 256 + r;
        unsigned int hi = p / W, wi = p - hi * W;
        b_src[j] = Xp + (hi * HP + wi) * CI + c4 * 8;    // + tap/ci offset
    }

    f32x4 acc[8][4];
#pragma unroll
    for (int mi = 0; mi < 8; ++mi)
#pragma unroll
        for (int ni = 0; ni < 4; ++ni)
            acc[mi][ni] = (f32x4){0.f, 0.f, 0.f, 0.f};

    auto stageA = [&](int kt, int k) {
        const int dst = ((kt & 1) * 2 + k) * 8192;
        const int off = kt * 64 + k * 32;
#pragma unroll
        for (int j = 0; j < 2; ++j)
            load_lds16(a_src[j] + off, &lds[dst + (j * 8 + wave) * 512]);
    };
    auto stageB = [&](int kt, int k) {
        const int dst = 32768 + ((kt & 1) * 2 + k) * 8192;
        const int tap = kt >> 2;                         // 0..8
        const int dh = (tap * 11) >> 5;                  // tap/3 for tap<=8
        const int dw = tap - dh * 3;
        const int off = (dh * HP + dw) * CI + (kt & 3) * 64 + k * 32;
#pragma unroll
        for (int j = 0; j < 2; ++j)
            load_lds16(b_src[j] + off, &lds[dst + (j * 8 + wave) * 512]);
    };
    // issue order matters for the vmcnt ladder: A0,B0 (k0) then A1,B1 (k1)
    auto stage8 = [&](int kt) {
        stageA(kt, 0); stageB(kt, 0);
        stageA(kt, 1); stageB(kt, 1);
    };

    bf16x8 afA[4], afB[4], bfr[4];

    // ---- prologue: stage K-tile 0; wait its k0 (keep k1 in flight) ----
    stage8(0);
    asm volatile("s_waitcnt vmcnt(4)" ::: "memory");
    __builtin_amdgcn_s_barrier();

    for (int kt = 0; kt < 36; ++kt) {
        const int b0 = (kt & 1) * 16384;                 // kappa = 0 region
        const int b1 = b0 + 8192;                        // kappa = 1 region
        const bool st = kt < 35;
        // ---- issue-early: ALL of kt+1's staging, 2-3 half-phases of slack ----
        if (st) stage8(kt + 1);
        // ---- kappa = 0 half ----
        RDALL(b0)
        MMH(0, afA)
        MMH(1, afB)
        if (st) asm volatile("s_waitcnt vmcnt(8)" ::: "memory");  // kt's k1 landed
        else    asm volatile("s_waitcnt vmcnt(0)" ::: "memory");
        __builtin_amdgcn_s_barrier();
        // ---- kappa = 1 half ----
        RDALL(b1)
        MMH(0, afA)
        MMH(1, afB)
        if (st) {
            asm volatile("s_waitcnt vmcnt(4)" ::: "memory");      // kt+1's k0 landed
            __builtin_amdgcn_s_barrier();                         // seals P reads too
        }
    }

    // ---- epilogue: C/D layout col = lane&15 (n=p), row = quad*4 + reg (m=co) ----
    const int pcol = Nb * 256 + wn * 64 + ln15;
    const int corow = wm * 128 + quad * 4;
#pragma unroll
    for (int mi = 0; mi < 8; ++mi)
#pragma unroll
        for (int ni = 0; ni < 4; ++ni)
#pragma unroll
            for (int r = 0; r < 4; ++r)
                out[(corow + mi * 16 + r) * NPOS + pcol + ni * 16] = acc[mi][ni][r];
}

extern "C" void kernel_launch(void* const* d_in, const int* in_sizes, int n_in,
                              void* d_out, int out_size, void* d_ws, size_t ws_size,
                              hipStream_t stream) {
    const float* x = (const float*)d_in[0];       // [1,256,224,224]
    const float* w = (const float*)d_in[1];       // [256,256,3,3]
    float* out = (float*)d_out;                   // [256,224,224]

    unsigned short* xp = (unsigned short*)d_ws;        // 13,075,456 shorts
    unsigned short* ap = xp + XP_ELEMS;                // 589,824 shorts

    prep_kernel<<<XT_BLOCKS + WT_BLOCKS + 113, 256, 0, stream>>>(x, w, ap, xp);
    gemm_conv_kernel<<<dim3(NPOS / 256), 512, 0, stream>>>(ap, xp, out);
}

// Round 11
// 160.299 us; speedup vs baseline: 1.0324x; 1.0324x over previous
//
#include <hip/hip_runtime.h>

// Conv2d 3x3 pad1 stride1, x[1,256,224,224] f32, w[256,256,3,3] f32 -> out[256,224,224] f32
// Implicit GEMM: M=256 (co), N=50176 (h*224+w), K=2304 (tap-major: k = (dh*3+dw)*256 + ci)
// R17: register-level fragment double-buffer on the R13 champion. R13's time = MFMA floor
//      (89K cyc) + LDS-read time (83K cyc) SERIALIZED: every half did read->lgkm0->MFMA on
//      its own reads. New: BK=32, 4 LDS buffers (64KB), stage depth 3; body kt = {stage
//      kt+3 ; prefetch frags(kt+1) into spare reg set (12 ds_read) ; 32 MFMA on frags
//      read LAST body ; vmcnt(4) ; barrier}. MFMAs don't consume this body's reads ->
//      LDS pipe hides under MFMA pipe. Swizzle/layout/acc-order identical to R13
//      (conflicts must stay 0, output bitwise-same). Two named frag sets (no dyn idx).
// Ladder: tile kt+1 retired by end of body kt-1 (vmcnt(4) retires kt+1 when kt+2 is the
//      only newer group); WAR on region (kt+3)&3 sealed by barrier at kt-2-end.
//      Tail: end-69 vmcnt(0); bodies 70,71 barrier-free (no writers remain).

#define H 224
#define W 224
#define NPOS (H*W)          // 50176
#define CI 256
#define CO 256
#define KDIM 2304
#define HP 226              // padded
#define XP_ELEMS (HP*HP*CI) // 13,075,456 shorts
#define AP_ELEMS (CO*KDIM)  // 589,824 shorts

typedef __bf16 bf16x8 __attribute__((ext_vector_type(8)));
typedef float f32x4 __attribute__((ext_vector_type(4)));
typedef unsigned short u16x4 __attribute__((ext_vector_type(4)));
typedef unsigned short u16x8 __attribute__((ext_vector_type(8)));

__device__ __forceinline__ unsigned short f2bf(float f) {
    unsigned int u = __float_as_uint(f);
    u += 0x7fff + ((u >> 16) & 1);   // round-to-nearest-even
    return (unsigned short)(u >> 16);
}

__device__ __forceinline__ void load_lds16(const unsigned short* g, unsigned short* l) {
    __builtin_amdgcn_global_load_lds(
        (const __attribute__((address_space(1))) void*)g,
        (__attribute__((address_space(3))) void*)l,
        16, 0, 0);
}

// ---- fused prep (unchanged from R8): xtrans + weight transform + border zero ----
#define XT_BLOCKS 3136      // 784 * 4
#define WT_BLOCKS 256
#define BORDER_V8 28800     // 230,400 shorts / 8
#define ROW_V8 7232         // 226*256/8
__global__ void prep_kernel(const float* __restrict__ x, const float* __restrict__ w,
                            unsigned short* __restrict__ ap, unsigned short* __restrict__ xp) {
    __shared__ unsigned short smem[64 * 68];
    const int bx = blockIdx.x;
    const int t = threadIdx.x;

    if (bx < XT_BLOCKS) {
        const unsigned int pBase = (unsigned int)(bx % 784) * 64;
        const unsigned int ciBase = (unsigned int)(bx / 784) * 64;
        {
            const int p4 = (t & 15) * 4;
            const int c0 = t >> 4;               // 0..15
#pragma unroll
            for (int i = 0; i < 4; ++i) {
                const int ci_l = c0 + i * 16;
                const f32x4 v = *(const f32x4*)&x[(ciBase + ci_l) * NPOS + pBase + p4];
                u16x4 s;
                s[0] = f2bf(v[0]); s[1] = f2bf(v[1]); s[2] = f2bf(v[2]); s[3] = f2bf(v[3]);
                *(u16x4*)&smem[ci_l * 68 + p4] = s;
            }
        }
        __syncthreads();
        {
            const int ci0 = (t & 7) * 8;
            const int pr = t >> 3;               // 0..31
#pragma unroll
            for (int j = 0; j < 2; ++j) {
                const int p_l = pr + j * 32;
                const unsigned int p = pBase + p_l;
                const unsigned int hi = p / W, wi = p - hi * W;
                u16x8 v;
#pragma unroll
                for (int k = 0; k < 8; ++k) v[k] = smem[(ci0 + k) * 68 + p_l];
                *(u16x8*)&xp[((hi + 1) * HP + (wi + 1)) * CI + ciBase + ci0] = v;
            }
        }
    } else if (bx < XT_BLOCKS + WT_BLOCKS) {
        const int co = bx - XT_BLOCKS;
        const float* wc = w + co * KDIM;
#pragma unroll
        for (int i = 0; i < 9; ++i)
            smem[i * 256 + t] = f2bf(wc[i * 256 + t]);
        __syncthreads();
        unsigned short* apc = ap + co * KDIM;
#pragma unroll
        for (int tap = 0; tap < 9; ++tap)
            apc[tap * 256 + t] = smem[t * 9 + tap];
    } else {
        const int idx = (bx - XT_BLOCKS - WT_BLOCKS) * 256 + t;
        if (idx < BORDER_V8) {
            unsigned short* p;
            if (idx < 2 * ROW_V8) {
                const int r = idx / ROW_V8;
                const int off = idx - r * ROW_V8;
                p = xp + r * (225 * HP * CI) + off * 8;
            } else {
                const int i2 = idx - 2 * ROW_V8;
                const int seg = i2 >> 5;
                const int o = i2 & 31;
                const int hp = 1 + (seg >> 1);
                const int wp = (seg & 1) * 225;
                p = xp + (hp * HP + wp) * CI + o * 8;
            }
            *(u16x8*)p = (u16x8){0, 0, 0, 0, 0, 0, 0, 0};
        }
    }
}

// ---- implicit GEMM, 256x256 tile, BK=32, 8 waves (2Mx4N), wave-tile 128x64 ----
// LDS (shorts): A regions [kt&3]*8192 at [0,32768); B at +32768. Region = 256 rows x
//   32 shorts; slot s of row r holds chunk s ^ ((r&15)>>1 & 3); source pre-swizzle
//   c4 = (l&3)^((l>>3)&3); read slot quad^((ln15>>1)&3). Proven 0-conflict (R12/R13).
// Per body kt: stage(kt+3) [4 gload_lds]; prefetch frags(kt+1) [12 ds_read_b128];
//   32 MFMA 16x16x32 on frags from body kt-1; vmcnt(4); s_barrier.

#define READF(afX, bfX, base)                                                   \
    _Pragma("unroll")                                                           \
    for (int mi = 0; mi < 8; ++mi)                                              \
        afX[mi] = *(const bf16x8*)&lds[(base) + arow + mi * 512];               \
    _Pragma("unroll")                                                           \
    for (int ni = 0; ni < 4; ++ni)                                              \
        bfX[ni] = *(const bf16x8*)&lds[(base) + brow + ni * 512];

#define MFMA32(afX, bfX)                                                        \
    __builtin_amdgcn_s_setprio(1);                                              \
    _Pragma("unroll")                                                           \
    for (int mi = 0; mi < 8; ++mi)                                              \
        _Pragma("unroll")                                                       \
        for (int ni = 0; ni < 4; ++ni)                                          \
            acc[mi][ni] = __builtin_amdgcn_mfma_f32_16x16x32_bf16(              \
                afX[mi], bfX[ni], acc[mi][ni], 0, 0, 0);                        \
    __builtin_amdgcn_s_setprio(0);

__global__ __launch_bounds__(512, 1) void gemm_conv_kernel(
    const unsigned short* __restrict__ Ap,   // [256][2304] bf16
    const unsigned short* __restrict__ Xp,   // [226][226][256] bf16
    float* __restrict__ out)                 // [256][50176]
{
    __shared__ unsigned short lds[32768 * 2];  // 64 KB: A 4 regions | B 4 regions

    const int tid = threadIdx.x;
    const int Nb = blockIdx.x;               // 0..195
    const int wave = tid >> 6;               // 0..7
    const int wm = wave >> 2;                // 0..1 (M half: 128 rows)
    const int wn = wave & 3;                 // 0..3 (N quarter: 64 cols)
    const int lane = tid & 63;
    const int ln15 = lane & 15;
    const int quad = lane >> 4;
    const int slot8 = (quad ^ ((ln15 >> 1) & 3)) * 8;    // proven conflict-free
    const int arow = (wm * 128 + ln15) * 32 + slot8;     // + mi*512
    const int brow = 32768 + (wn * 64 + ln15) * 32 + slot8;  // + ni*512

    // ---- staging sources (inverse swizzle pre-applied; unchanged) ----
    const int c4 = (tid & 3) ^ ((tid >> 3) & 3);
    const unsigned short* a_src[2];
    const unsigned short* b_src[2];
#pragma unroll
    for (int j = 0; j < 2; ++j) {
        const int r = j * 128 + (tid >> 2);              // 0..255
        a_src[j] = Ap + r * KDIM + c4 * 8;               // + kt*32
        unsigned int p = Nb * 256 + r;
        unsigned int hi = p / W, wi = p - hi * W;
        b_src[j] = Xp + (hi * HP + wi) * CI + c4 * 8;    // + tap/ci offset
    }

    f32x4 acc[8][4];
#pragma unroll
    for (int mi = 0; mi < 8; ++mi)
#pragma unroll
        for (int ni = 0; ni < 4; ++ni)
            acc[mi][ni] = (f32x4){0.f, 0.f, 0.f, 0.f};

    auto stageT = [&](int kt) {
        const int da = (kt & 3) * 8192;
        const int db = 32768 + (kt & 3) * 8192;
        const int aoff = kt * 32;
        const int tap = kt >> 3;                         // 0..8 (8 tiles per tap)
        const int dh = (tap * 11) >> 5;                  // tap/3 for tap<=8
        const int dw = tap - dh * 3;
        const int boff = (dh * HP + dw) * CI + (kt & 7) * 32;
#pragma unroll
        for (int j = 0; j < 2; ++j) {
            load_lds16(a_src[j] + aoff, &lds[da + (j * 8 + wave) * 512]);
            load_lds16(b_src[j] + boff, &lds[db + (j * 8 + wave) * 512]);
        }
    };

    bf16x8 af0[8], bf0[4], af1[8], bf1[4];   // two named fragment sets (no dyn idx)

    // ---- prologue: stage tiles 0,1,2; retire 0 AND 1; read frags(0) into set0 ----
    stageT(0); stageT(1); stageT(2);
    asm volatile("s_waitcnt vmcnt(4)" ::: "memory");     // tiles 0,1 landed; 2 in flight
    __builtin_amdgcn_s_barrier();
    READF(af0, bf0, 0)

    for (int kt = 0; kt < 72; kt += 2) {
        // ---- body kt (even): compute set0, prefetch (kt+1) into set1 ----
        if (kt <= 68) stageT(kt + 3);
        READF(af1, bf1, ((kt + 1) & 3) * 8192)
        MFMA32(af0, bf0)
        if (kt <= 68) {
            asm volatile("s_waitcnt vmcnt(4)" ::: "memory");   // retire tile kt+2
            __builtin_amdgcn_s_barrier();
        }
        // ---- body kt+1 (odd): compute set1, prefetch (kt+2) into set0 ----
        if (kt + 1 <= 68) stageT(kt + 4);
        if (kt + 1 < 71) { READF(af0, bf0, ((kt + 2) & 3) * 8192) }
        MFMA32(af1, bf1)
        if (kt + 1 <= 68) {
            asm volatile("s_waitcnt vmcnt(4)" ::: "memory");   // retire tile kt+3
            __builtin_amdgcn_s_barrier();
        } else if (kt + 1 == 69) {
            asm volatile("s_waitcnt vmcnt(0)" ::: "memory");   // retire tile 71
            __builtin_amdgcn_s_barrier();
        }
    }

    // ---- epilogue: C/D layout col = lane&15 (n=p), row = quad*4 + reg (m=co) ----
    const int pcol = Nb * 256 + wn * 64 + ln15;
    const int corow = wm * 128 + quad * 4;
#pragma unroll
    for (int mi = 0; mi < 8; ++mi)
#pragma unroll
        for (int ni = 0; ni < 4; ++ni)
#pragma unroll
            for (int r = 0; r < 4; ++r)
                out[(corow + mi * 16 + r) * NPOS + pcol + ni * 16] = acc[mi][ni][r];
}

extern "C" void kernel_launch(void* const* d_in, const int* in_sizes, int n_in,
                              void* d_out, int out_size, void* d_ws, size_t ws_size,
                              hipStream_t stream) {
    const float* x = (const float*)d_in[0];       // [1,256,224,224]
    const float* w = (const float*)d_in[1];       // [256,256,3,3]
    float* out = (float*)d_out;                   // [256,224,224]

    unsigned short* xp = (unsigned short*)d_ws;        // 13,075,456 shorts
    unsigned short* ap = xp + XP_ELEMS;                // 589,824 shorts

    prep_kernel<<<XT_BLOCKS + WT_BLOCKS + 113, 256, 0, stream>>>(x, w, ap, xp);
    gemm_conv_kernel<<<dim3(NPOS / 256), 512, 0, stream>>>(ap, xp, out);
}

// Round 12
// 152.705 us; speedup vs baseline: 1.0837x; 1.0497x over previous
//
#include <hip/hip_runtime.h>

// Conv2d 3x3 pad1 stride1, x[1,256,224,224] f32, w[256,256,3,3] f32 -> out[256,224,224] f32
// Implicit GEMM: M=256 (co), N=50176 (h*224+w), K=2304 (tap-major: k = (dh*3+dw)*256 + ci)
// R18: BN=224 re-tiling of the R13 champion (71.1us, conflicts=0). 50176 = 224*224 ->
//      grid 224 blocks = ONE PER CU (87.5% machine, single round) vs 196/256 (76.6%).
//      Gemm is CU-bound (24% HBM), so idle CUs were pure loss. Wave decomp 4Mx2N,
//      wave-tile 64x112 (4 A-frags + 7 B-frags, 28 MFMA/kappa). Everything else
//      byte-identical to R13: LDS regions (B rows 224-255 over-staged by the unchanged
//      thread mapping, never read; worst-case source spill lands in ap workspace - safe),
//      proven swizzle, vmcnt(4)/barrier ladder, ascending-k accumulation.

#define H 224
#define W 224
#define NPOS (H*W)          // 50176
#define CI 256
#define CO 256
#define KDIM 2304
#define HP 226              // padded
#define XP_ELEMS (HP*HP*CI) // 13,075,456 shorts
#define AP_ELEMS (CO*KDIM)  // 589,824 shorts
#define BN 224              // N-tile: 50176/224 = 224 blocks = 1/CU

typedef __bf16 bf16x8 __attribute__((ext_vector_type(8)));
typedef float f32x4 __attribute__((ext_vector_type(4)));
typedef unsigned short u16x4 __attribute__((ext_vector_type(4)));
typedef unsigned short u16x8 __attribute__((ext_vector_type(8)));

__device__ __forceinline__ unsigned short f2bf(float f) {
    unsigned int u = __float_as_uint(f);
    u += 0x7fff + ((u >> 16) & 1);   // round-to-nearest-even
    return (unsigned short)(u >> 16);
}

__device__ __forceinline__ void load_lds16(const unsigned short* g, unsigned short* l) {
    __builtin_amdgcn_global_load_lds(
        (const __attribute__((address_space(1))) void*)g,
        (__attribute__((address_space(3))) void*)l,
        16, 0, 0);
}

// ---- fused prep (unchanged from R8): xtrans + weight transform + border zero ----
#define XT_BLOCKS 3136      // 784 * 4
#define WT_BLOCKS 256
#define BORDER_V8 28800     // 230,400 shorts / 8
#define ROW_V8 7232         // 226*256/8
__global__ void prep_kernel(const float* __restrict__ x, const float* __restrict__ w,
                            unsigned short* __restrict__ ap, unsigned short* __restrict__ xp) {
    __shared__ unsigned short smem[64 * 68];
    const int bx = blockIdx.x;
    const int t = threadIdx.x;

    if (bx < XT_BLOCKS) {
        const unsigned int pBase = (unsigned int)(bx % 784) * 64;
        const unsigned int ciBase = (unsigned int)(bx / 784) * 64;
        {
            const int p4 = (t & 15) * 4;
            const int c0 = t >> 4;               // 0..15
#pragma unroll
            for (int i = 0; i < 4; ++i) {
                const int ci_l = c0 + i * 16;
                const f32x4 v = *(const f32x4*)&x[(ciBase + ci_l) * NPOS + pBase + p4];
                u16x4 s;
                s[0] = f2bf(v[0]); s[1] = f2bf(v[1]); s[2] = f2bf(v[2]); s[3] = f2bf(v[3]);
                *(u16x4*)&smem[ci_l * 68 + p4] = s;
            }
        }
        __syncthreads();
        {
            const int ci0 = (t & 7) * 8;
            const int pr = t >> 3;               // 0..31
#pragma unroll
            for (int j = 0; j < 2; ++j) {
                const int p_l = pr + j * 32;
                const unsigned int p = pBase + p_l;
                const unsigned int hi = p / W, wi = p - hi * W;
                u16x8 v;
#pragma unroll
                for (int k = 0; k < 8; ++k) v[k] = smem[(ci0 + k) * 68 + p_l];
                *(u16x8*)&xp[((hi + 1) * HP + (wi + 1)) * CI + ciBase + ci0] = v;
            }
        }
    } else if (bx < XT_BLOCKS + WT_BLOCKS) {
        const int co = bx - XT_BLOCKS;
        const float* wc = w + co * KDIM;
#pragma unroll
        for (int i = 0; i < 9; ++i)
            smem[i * 256 + t] = f2bf(wc[i * 256 + t]);
        __syncthreads();
        unsigned short* apc = ap + co * KDIM;
#pragma unroll
        for (int tap = 0; tap < 9; ++tap)
            apc[tap * 256 + t] = smem[t * 9 + tap];
    } else {
        const int idx = (bx - XT_BLOCKS - WT_BLOCKS) * 256 + t;
        if (idx < BORDER_V8) {
            unsigned short* p;
            if (idx < 2 * ROW_V8) {
                const int r = idx / ROW_V8;
                const int off = idx - r * ROW_V8;
                p = xp + r * (225 * HP * CI) + off * 8;
            } else {
                const int i2 = idx - 2 * ROW_V8;
                const int seg = i2 >> 5;
                const int o = i2 & 31;
                const int hp = 1 + (seg >> 1);
                const int wp = (seg & 1) * 225;
                p = xp + (hp * HP + wp) * CI + o * 8;
            }
            *(u16x8*)p = (u16x8){0, 0, 0, 0, 0, 0, 0, 0};
        }
    }
}

// ---- implicit GEMM, 256x224 tile, BK=64, 8 waves (4Mx2N), wave-tile 64x112 ----
// LDS (shorts): A[pi][kappa] = 4 regions x 8192 at [0,32768); B likewise at +32768
//   (B rows 224..255 of each region are over-staged, never read).
//   Slot s of row r holds chunk s ^ ((r&15)>>1 & 3); source pre-swizzle
//   c4 = (l&3)^((l>>3)&3); read slot quad^((ln15>>1)&3). Proven 0-conflict (R12/R13).
// Per kappa half (K=32): {read af[0..1]+bf[0..6] (9 ds); stageA(kt+1,k); 14 MFMA
//   (mi 0-1); read af[2..3] (2 ds); stageB(kt+1,k); 14 MFMA (mi 2-3); vmcnt(4); bar}.
// vmcnt ladder identical to R13 (4 loads/thread/kappa, issue order A,B per kappa):
//   kappa0-end: outstanding = kt.k1(4)+kt+1.k0(4) -> vmcnt(4) retires kt's k1.
//   kappa1-end: outstanding = kt+1's 8 -> vmcnt(4) retires kt+1's k0.
//   Tail kt=35: kappa0-end vmcnt(0), no trailing wait.

#define MFMA14(miA, miB)                                                        \
    __builtin_amdgcn_s_setprio(1);                                              \
    _Pragma("unroll")                                                           \
    for (int ni = 0; ni < 7; ++ni) {                                            \
        acc[miA][ni] = __builtin_amdgcn_mfma_f32_16x16x32_bf16(                 \
            af[miA], bf[ni], acc[miA][ni], 0, 0, 0);                            \
        acc[miB][ni] = __builtin_amdgcn_mfma_f32_16x16x32_bf16(                 \
            af[miB], bf[ni], acc[miB][ni], 0, 0, 0);                            \
    }                                                                           \
    __builtin_amdgcn_s_setprio(0);

__global__ __launch_bounds__(512, 1) void gemm_conv_kernel(
    const unsigned short* __restrict__ Ap,   // [256][2304] bf16
    const unsigned short* __restrict__ Xp,   // [226][226][256] bf16
    float* __restrict__ out)                 // [256][50176]
{
    __shared__ unsigned short lds[65536];    // 128 KB

    const int tid = threadIdx.x;
    const int Nb = blockIdx.x;               // 0..223
    const int wave = tid >> 6;               // 0..7
    const int wm = wave >> 1;                // 0..3 (M quarter: 64 rows)
    const int wn = wave & 1;                 // 0..1 (N half: 112 cols)
    const int lane = tid & 63;
    const int ln15 = lane & 15;
    const int quad = lane >> 4;
    const int slot8 = (quad ^ ((ln15 >> 1) & 3)) * 8;    // proven conflict-free
    const int arow = (wm * 64 + ln15) * 32 + slot8;      // + mi*512
    const int brow = 32768 + (wn * 112 + ln15) * 32 + slot8;  // + ni*512

    // ---- staging sources (inverse swizzle pre-applied; mapping unchanged) ----
    const int c4 = (tid & 3) ^ ((tid >> 3) & 3);
    const unsigned short* a_src[2];
    const unsigned short* b_src[2];
#pragma unroll
    for (int j = 0; j < 2; ++j) {
        const int r = j * 128 + (tid >> 2);              // 0..255
        a_src[j] = Ap + r * KDIM + c4 * 8;               // + kt*64 + kappa*32
        unsigned int p = Nb * BN + r;                    // rows 224-255: over-stage (safe)
        unsigned int hi = p / W, wi = p - hi * W;
        b_src[j] = Xp + (hi * HP + wi) * CI + c4 * 8;    // + tap/ci offset
    }

    f32x4 acc[4][7];
#pragma unroll
    for (int mi = 0; mi < 4; ++mi)
#pragma unroll
        for (int ni = 0; ni < 7; ++ni)
            acc[mi][ni] = (f32x4){0.f, 0.f, 0.f, 0.f};

    auto stageA = [&](int kt, int k) {
        const int dst = ((kt & 1) * 2 + k) * 8192;
        const int off = kt * 64 + k * 32;
#pragma unroll
        for (int j = 0; j < 2; ++j)
            load_lds16(a_src[j] + off, &lds[dst + (j * 8 + wave) * 512]);
    };
    auto stageB = [&](int kt, int k) {
        const int dst = 32768 + ((kt & 1) * 2 + k) * 8192;
        const int tap = kt >> 2;                         // 0..8
        const int dh = (tap * 11) >> 5;                  // tap/3 for tap<=8
        const int dw = tap - dh * 3;
        const int off = (dh * HP + dw) * CI + (kt & 3) * 64 + k * 32;
#pragma unroll
        for (int j = 0; j < 2; ++j)
            load_lds16(b_src[j] + off, &lds[dst + (j * 8 + wave) * 512]);
    };

    bf16x8 af[4], bf[7];

#define RD_MAIN(base)                                                           \
    _Pragma("unroll")                                                           \
    for (int mi = 0; mi < 2; ++mi)                                              \
        af[mi] = *(const bf16x8*)&lds[(base) + arow + mi * 512];                \
    _Pragma("unroll")                                                           \
    for (int ni = 0; ni < 7; ++ni)                                              \
        bf[ni] = *(const bf16x8*)&lds[(base) + brow + ni * 512];

#define RD_TAILA(base)                                                          \
    _Pragma("unroll")                                                           \
    for (int mi = 2; mi < 4; ++mi)                                              \
        af[mi] = *(const bf16x8*)&lds[(base) + arow + mi * 512];

    // ---- prologue: stage K-tile 0 (Ak0,Bk0,Ak1,Bk1 = 8 loads); keep k1 in flight ----
    stageA(0, 0); stageB(0, 0); stageA(0, 1); stageB(0, 1);
    asm volatile("s_waitcnt vmcnt(4)" ::: "memory");     // Ak0,Bk0 landed
    __builtin_amdgcn_s_barrier();

    for (int kt = 0; kt < 36; ++kt) {
        const int b0 = (kt & 1) * 16384;                 // kappa = 0 region
        const int b1 = b0 + 8192;                        // kappa = 1 region
        const bool st = kt < 35;
        // ---- kappa = 0 half: free-run ----
        RD_MAIN(b0)
        if (st) stageA(kt + 1, 0);
        MFMA14(0, 1)
        RD_TAILA(b0)
        if (st) stageB(kt + 1, 0);
        MFMA14(2, 3)
        if (st) asm volatile("s_waitcnt vmcnt(4)" ::: "memory");
        else    asm volatile("s_waitcnt vmcnt(0)" ::: "memory");
        __builtin_amdgcn_s_barrier();                    // kt's k1 landed, wave-global
        // ---- kappa = 1 half ----
        RD_MAIN(b1)
        if (st) stageA(kt + 1, 1);
        MFMA14(0, 1)
        RD_TAILA(b1)
        if (st) stageB(kt + 1, 1);
        MFMA14(2, 3)
        if (st) {
            asm volatile("s_waitcnt vmcnt(4)" ::: "memory");
            __builtin_amdgcn_s_barrier();                // kt+1's k0 landed; seals reads
        }
    }

    // ---- epilogue: C/D layout col = lane&15 (n=p), row = quad*4 + reg (m=co) ----
    const int pcol = Nb * BN + wn * 112 + ln15;
    const int corow = wm * 64 + quad * 4;
#pragma unroll
    for (int mi = 0; mi < 4; ++mi)
#pragma unroll
        for (int ni = 0; ni < 7; ++ni)
#pragma unroll
            for (int r = 0; r < 4; ++r)
                out[(corow + mi * 16 + r) * NPOS + pcol + ni * 16] = acc[mi][ni][r];
}

extern "C" void kernel_launch(void* const* d_in, const int* in_sizes, int n_in,
                              void* d_out, int out_size, void* d_ws, size_t ws_size,
                              hipStream_t stream) {
    const float* x = (const float*)d_in[0];       // [1,256,224,224]
    const float* w = (const float*)d_in[1];       // [256,256,3,3]
    float* out = (float*)d_out;                   // [256,224,224]

    unsigned short* xp = (unsigned short*)d_ws;        // 13,075,456 shorts
    unsigned short* ap = xp + XP_ELEMS;                // 589,824 shorts

    prep_kernel<<<XT_BLOCKS + WT_BLOCKS + 113, 256, 0, stream>>>(x, w, ap, xp);
    gemm_conv_kernel<<<dim3(NPOS / BN), 512, 0, stream>>>(ap, xp, out);
}